// Round 1
// baseline (275.331 us; speedup 1.0000x reference)
//
#include <hip/hip_runtime.h>
#include <math.h>

#define GAIN_CAP 0.99f
#define EPSV 1e-4f

static constexpr int B = 4, C = 128, H = 256, W = 256, O = 16, M = 32;
static constexpr int HW = H * W;

typedef float   vfloat4 __attribute__((ext_vector_type(4)));
typedef _Float16 half4v __attribute__((ext_vector_type(4)));
typedef _Float16 half8v __attribute__((ext_vector_type(8)));

// ws layout: sfp[B][HW] as half4 (8 B/px) = 2 MB, then gains[B*C*3], invd[C*3]
static constexpr int SFP_FLOATS = B * HW * 2;   // half4 == 2 floats
static constexpr int G_SZ = B * C * 3;

__device__ __forceinline__ float softplusf(float x) {
    return log1pf(expf(-fabsf(x))) + fmaxf(x, 0.0f);
}
__device__ __forceinline__ float clampg(float v) {
    return fminf(fmaxf(v, 0.0f), GAIN_CAP);
}
__device__ __forceinline__ float fast_tanh(float x) {
    // tanh(x) = 1 - 2/(e^{2x}+1); __expf -> v_exp_f32, rcp -> v_rcp_f32.
    float e = __expf(2.0f * x);
    return 1.0f - 2.0f * __builtin_amdgcn_rcpf(e + 1.0f);
}

// steer fields -> packed half4 {s0,s1,s2,0}; per-(b,c) gains + invd in block 0.
// 4 px per thread: float4 loads (1 KB/wave/stream), 32 B packed stores.
__global__ void __launch_bounds__(256)
steer_kernel(const float* __restrict__ steer,   // [B,O,HW]
             const float* __restrict__ steer_w, // [4,O]
             const float* __restrict__ r_center,
             const float* __restrict__ r_h,
             const float* __restrict__ r_v,
             const float* __restrict__ r_d,
             const float* __restrict__ g_h,
             const float* __restrict__ g_v,
             const float* __restrict__ g_d,
             const float* __restrict__ modulation, // [B,M]
             const float* __restrict__ mod_w,      // [3,M]
             half4v* __restrict__ sfp,             // [B,HW]
             float* __restrict__ gains,            // [B,C,3]
             float* __restrict__ invd)             // [C,3]
{
    if (blockIdx.x == 0 && threadIdx.x < C) {
        int c = threadIdx.x;
        float rc = softplusf(r_center[c]) + EPSV;
        invd[c * 3 + 0] = 1.0f / (rc + softplusf(r_h[c]) + EPSV);
        invd[c * 3 + 1] = 1.0f / (rc + softplusf(r_v[c]) + EPSV);
        invd[c * 3 + 2] = 1.0f / (2.0f * (rc + softplusf(r_d[c]) + EPSV));
        float th = tanhf(g_h[c]), tv = tanhf(g_v[c]), td = tanhf(g_d[c]);
        for (int b = 0; b < B; ++b) {
            float a0 = 0.f, a1 = 0.f, a2 = 0.f;
#pragma unroll
            for (int m = 0; m < M; ++m) {
                float mv = modulation[b * M + m];
                a0 += mv * mod_w[0 * M + m];
                a1 += mv * mod_w[1 * M + m];
                a2 += mv * mod_w[2 * M + m];
            }
            gains[(b * C + c) * 3 + 0] = clampg(th * (1.0f + 0.1f * tanhf(a0)));
            gains[(b * C + c) * 3 + 1] = clampg(tv * (1.0f + 0.1f * tanhf(a1)));
            gains[(b * C + c) * 3 + 2] = clampg(td * (1.0f + 0.1f * tanhf(a2)));
        }
    }

    int idx = blockIdx.x * 256 + threadIdx.x;  // 0 .. B*HW/4-1  (256 blocks)
    int b   = idx >> 14;                       // HW/4 = 16384 groups per b
    int g   = idx & 16383;
    const float4* sp = (const float4*)(steer + ((size_t)b * O << 16)) + g;

    float4 a0 = {0.f, 0.f, 0.f, 0.f}, a1 = a0, a2 = a0;
#pragma unroll
    for (int o = 0; o < O; ++o) {
        float4 v = sp[(size_t)o << 14];
        float w0 = steer_w[o], w1 = steer_w[O + o], w2 = steer_w[2 * O + o];
        a0.x += v.x * w0; a0.y += v.y * w0; a0.z += v.z * w0; a0.w += v.w * w0;
        a1.x += v.x * w1; a1.y += v.y * w1; a1.z += v.z * w1; a1.w += v.w * w1;
        a2.x += v.x * w2; a2.y += v.y * w2; a2.z += v.z * w2; a2.w += v.w * w2;
    }
    half8v oA, oB;
    oA[0] = (_Float16)fast_tanh(a0.x); oA[1] = (_Float16)fast_tanh(a1.x);
    oA[2] = (_Float16)fast_tanh(a2.x); oA[3] = (_Float16)0.f;
    oA[4] = (_Float16)fast_tanh(a0.y); oA[5] = (_Float16)fast_tanh(a1.y);
    oA[6] = (_Float16)fast_tanh(a2.y); oA[7] = (_Float16)0.f;
    oB[0] = (_Float16)fast_tanh(a0.z); oB[1] = (_Float16)fast_tanh(a1.z);
    oB[2] = (_Float16)fast_tanh(a2.z); oB[3] = (_Float16)0.f;
    oB[4] = (_Float16)fast_tanh(a0.w); oB[5] = (_Float16)fast_tanh(a1.w);
    oB[6] = (_Float16)fast_tanh(a2.w); oB[7] = (_Float16)0.f;
    half8v* op = (half8v*)sfp + ((size_t)idx << 1);
    op[0] = oA;
    op[1] = oB;
}

__device__ __forceinline__ vfloat4 row_compute(
    const float4& u, const float4& cc, const float4& d,
    float uL, float uR, float cL, float cR, float dL, float dR,
    float ih, float iv, float idg, float g0, float g1, float g2,
    const float (&s0)[4], const float (&s1)[4], const float (&s2)[4])
{
    float cA[4]  = {cc.x, cc.y, cc.z, cc.w};
    float uA[4]  = {u.x, u.y, u.z, u.w};
    float dA[4]  = {d.x, d.y, d.z, d.w};
    float crA[4] = {cc.y, cc.z, cc.w, cR};
    float clA[4] = {cL, cc.x, cc.y, cc.z};
    float urA[4] = {u.y, u.z, u.w, uR};
    float ulA[4] = {uL, u.x, u.y, u.z};
    float drA[4] = {d.y, d.z, d.w, dR};
    float dlA[4] = {dL, d.x, d.y, d.z};
    vfloat4 o;
#pragma unroll
    for (int j = 0; j < 4; ++j) {
        float fh = (crA[j] + clA[j] - 2.0f * cA[j]) * ih;
        float fv = (uA[j] + dA[j] - 2.0f * cA[j]) * iv;
        float fd = (drA[j] + dlA[j] + urA[j] + ulA[j] - 4.0f * cA[j]) * idg;
        float gh = clampg(g0 * (1.0f + 0.2f * s0[j]));
        float gv = clampg(g1 * (1.0f + 0.2f * s1[j]));
        float gd = clampg(g2 * (1.0f + 0.2f * s2[j]));
        o[j] = cA[j] + gh * fh + gv * fv + gd * fd;
    }
    return o;
}

#define LDROW(p, h) (((const float4*)((p) + ((h) << 8)))[lane])

// One wave == one row (64 lanes x float4 == W). NCH=2 channels per block share
// sf rows; RPW=8 rows per wave; u/c/d rows rotate in registers.
// Software-pipelined: row r+1's d/sf loads are issued BEFORE row r's compute,
// so each wave keeps ~4 KB in flight while the VALU works (latency fix).
__global__ void __launch_bounds__(256)
main_kernel(const float* __restrict__ x,      // [B,C,H,W]
            const half4v* __restrict__ sfp,   // [B,HW]
            const float* __restrict__ gains,  // [B,C,3]
            const float* __restrict__ invd,   // [C,3]
            float* __restrict__ out)
{
    constexpr int RPW = 8;
    int lane  = threadIdx.x & 63;
    int wave  = threadIdx.x >> 6;
    int gid   = blockIdx.x;
    int strip = gid & 7;            // 8 strips of 32 rows -> 8 XCDs
    int cg    = (gid >> 3) & 63;    // channel pair
    int b     = gid >> 9;
    int bc0   = b * C + cg * 2;
    int c0    = bc0 & (C - 1);
    int h0    = strip * 32 + wave * RPW;

    const float* p0 = x + ((size_t)bc0 << 16);
    const float* p1 = p0 + HW;
    float* q0 = out + ((size_t)bc0 << 16);
    float* q1 = q0 + HW;
    const half4v* sfb = sfp + ((size_t)b << 16);

    float ih0 = invd[c0 * 3 + 0], iv0 = invd[c0 * 3 + 1], id0 = invd[c0 * 3 + 2];
    float ih1 = invd[c0 * 3 + 3], iv1 = invd[c0 * 3 + 4], id1 = invd[c0 * 3 + 5];
    float g00 = gains[bc0 * 3 + 0], g01 = gains[bc0 * 3 + 1], g02 = gains[bc0 * 3 + 2];
    float g10 = gains[bc0 * 3 + 3], g11 = gains[bc0 * 3 + 4], g12 = gains[bc0 * 3 + 5];

    int lp = (lane + 1) & 63, lm = (lane - 1) & 63;
    int hm = (h0 - 1) & 255;
    int hd = (h0 + 1) & 255;

    // prime the pipeline: u/c rows plus row 0's d and sf already in flight
    float4 u0  = LDROW(p0, hm), u1  = LDROW(p1, hm);
    float4 c0v = LDROW(p0, h0), c1v = LDROW(p1, h0);
    float4 d0  = LDROW(p0, hd), d1  = LDROW(p1, hd);
    const float4* sr0 = (const float4*)(sfb + ((size_t)h0 << 8));
    float4 sA = sr0[2 * lane], sB = sr0[2 * lane + 1];

    float u0R = __shfl(u0.x, lp), u0L = __shfl(u0.w, lm);
    float u1R = __shfl(u1.x, lp), u1L = __shfl(u1.w, lm);
    float c0R = __shfl(c0v.x, lp), c0L = __shfl(c0v.w, lm);
    float c1R = __shfl(c1v.x, lp), c1L = __shfl(c1v.w, lm);

#pragma unroll
    for (int r = 0; r < RPW; ++r) {
        int h = h0 + r;

        // issue next row's loads BEFORE touching this row's data
        float4 nd0 = d0, nd1 = d1, nsA = sA, nsB = sB;
        if (r + 1 < RPW) {
            int h2 = (h + 2) & 255;       // d row of iteration r+1 (wraps)
            nd0 = LDROW(p0, h2);
            nd1 = LDROW(p1, h2);
            const float4* srn = (const float4*)(sfb + ((size_t)(h + 1) << 8));
            nsA = srn[2 * lane];
            nsB = srn[2 * lane + 1];
        }

        float d0R = __shfl(d0.x, lp), d0L = __shfl(d0.w, lm);
        float d1R = __shfl(d1.x, lp), d1L = __shfl(d1.w, lm);

        half8v hA = __builtin_bit_cast(half8v, sA);
        half8v hB = __builtin_bit_cast(half8v, sB);
        float s0[4], s1[4], s2[4];
        s0[0] = (float)hA[0]; s1[0] = (float)hA[1]; s2[0] = (float)hA[2];
        s0[1] = (float)hA[4]; s1[1] = (float)hA[5]; s2[1] = (float)hA[6];
        s0[2] = (float)hB[0]; s1[2] = (float)hB[1]; s2[2] = (float)hB[2];
        s0[3] = (float)hB[4]; s1[3] = (float)hB[5]; s2[3] = (float)hB[6];

        vfloat4 o0 = row_compute(u0, c0v, d0, u0L, u0R, c0L, c0R, d0L, d0R,
                                 ih0, iv0, id0, g00, g01, g02, s0, s1, s2);
        vfloat4 o1 = row_compute(u1, c1v, d1, u1L, u1R, c1L, c1R, d1L, d1R,
                                 ih1, iv1, id1, g10, g11, g12, s0, s1, s2);
        __builtin_nontemporal_store(o0, (vfloat4*)(q0 + (h << 8)) + lane);
        __builtin_nontemporal_store(o1, (vfloat4*)(q1 + (h << 8)) + lane);

        u0 = c0v; u0R = c0R; u0L = c0L;
        u1 = c1v; u1R = c1R; u1L = c1L;
        c0v = d0; c0R = d0R; c0L = d0L;
        c1v = d1; c1R = d1R; c1L = d1L;
        d0 = nd0; d1 = nd1;
        sA = nsA; sB = nsB;
    }
}

extern "C" void kernel_launch(void* const* d_in, const int* in_sizes, int n_in,
                              void* d_out, int out_size, void* d_ws, size_t ws_size,
                              hipStream_t stream) {
    const float* x          = (const float*)d_in[0];
    const float* steer      = (const float*)d_in[1];
    const float* modulation = (const float*)d_in[2];
    const float* r_center   = (const float*)d_in[3];
    const float* r_horiz    = (const float*)d_in[4];
    const float* r_vert     = (const float*)d_in[5];
    const float* r_diag     = (const float*)d_in[6];
    const float* g_horiz    = (const float*)d_in[7];
    const float* g_vert     = (const float*)d_in[8];
    const float* g_diag     = (const float*)d_in[9];
    const float* steer_w    = (const float*)d_in[10];
    const float* mod_w      = (const float*)d_in[11];

    float* ws     = (float*)d_ws;
    half4v* sfp   = (half4v*)ws;
    float* gains  = ws + SFP_FLOATS;
    float* invd   = gains + G_SZ;
    float* out    = (float*)d_out;

    steer_kernel<<<(B * HW / 4) / 256, 256, 0, stream>>>(
        steer, steer_w, r_center, r_horiz, r_vert, r_diag,
        g_horiz, g_vert, g_diag, modulation, mod_w, sfp, gains, invd);
    main_kernel<<<B * (C / 2) * 8, 256, 0, stream>>>(x, sfp, gains, invd, out);
}